// Round 5
// baseline (129.950 us; speedup 1.0000x reference)
//
#include <hip/hip_runtime.h>
#include <math.h>

// x[32,3,512,512] f32 -> |1 - mean over (b,h,w) of min over (c, 20x20 window,
// replicate pad pl=9 pr=10)|.
//
// Single fused kernel, one barrier, 64x64 outputs/block (2048 blocks):
//   phase 1: channel-min + horizontal sliding-min(20) read straight from
//            global (coalesced float4, clamped aligned base), Gil-Werman
//            runs of 16; result -> LDS tile hm[83][66] (stride 66: float2
//            writes are exact 2-way bank = free; column reads conflict-free).
//            Replicate-pad rows baked in via row clamp.
//   phase 2: vertical sliding-min(20), Gil-Werman runs of 16, f32 accumulate.
//   finish:  block partial -> d_ws; last block (atomic ticket, fenced)
//            reduces all 2048 partials deterministically -> |1 - mean|.
// Counter is zeroed by a 4-byte hipMemsetAsync before the kernel each call.

#define BATCH 32
#define HH 512
#define WW 512
#define CH (HH * WW)
#define NBX 8
#define NBY 8
#define NBLK (NBX * NBY * BATCH)   // 2048
#define LSTR 66                    // LDS row stride in floats

__device__ __forceinline__ float fmin3(float a, float b, float c) {
    return fminf(fminf(a, b), c);
}

__launch_bounds__(256)
__global__ void dark_fused_kernel(const float* __restrict__ x,
                                  float* __restrict__ partials,
                                  unsigned* __restrict__ counter,
                                  float* __restrict__ out)
{
    __shared__ float hm[83 * LSTR];   // 21912 B
    __shared__ float red[4];
    __shared__ int lastflag;

    const int b  = blockIdx.z;
    const int h0 = blockIdx.y * 64;
    const int w0 = blockIdx.x * 64;
    const int t  = threadIdx.x;
    const float* xb = x + (size_t)b * 3 * CH;

    // ---- Phase 1: channel-min + horizontal min(20) -> LDS ----
    // 332 tasks: LDS row r (= clamped global row h0-9+r), quad q (16 cols)
    for (int task = t; task < 83 * 4; task += 256) {
        int r = task >> 2;
        int q = task & 3;
        int gr = h0 - 9 + r; gr = gr < 0 ? 0 : (gr > HH - 1 ? HH - 1 : gr);
        int jg0 = w0 + (q << 4);          // global col of first output
        int grun = jg0 >> 4;              // global run index 0..31
        const float* row = xb + gr * WW;
        int cb  = jg0 - 12;
        int cbc = cb < 0 ? 0 : (cb > WW - 40 ? WW - 40 : cb);  // 0 or 472
        const float4* p0 = (const float4*)(row + cbc);
        const float4* p1 = (const float4*)(row + cbc + CH);
        const float4* p2 = (const float4*)(row + cbc + 2 * CH);
        float e[40];
        #pragma unroll
        for (int k = 0; k < 10; ++k) {
            float4 a = p0[k], bb = p1[k], c = p2[k];
            e[4 * k + 0] = fmin3(a.x, bb.x, c.x);
            e[4 * k + 1] = fmin3(a.y, bb.y, c.y);
            e[4 * k + 2] = fmin3(a.z, bb.z, c.z);
            e[4 * k + 3] = fmin3(a.w, bb.w, c.w);
        }
        // w[d] = channel-min at clamped global col (jg0 + d - 9)
        float w[35];
        if (grun == 0) {
            #pragma unroll
            for (int d = 0; d < 35; ++d) w[d] = e[d < 9 ? 0 : d - 9];
        } else if (grun == 31) {
            #pragma unroll
            for (int d = 0; d < 35; ++d) w[d] = e[d + 15 > 39 ? 39 : d + 15];
        } else {
            #pragma unroll
            for (int d = 0; d < 35; ++d) w[d] = e[d + 3];
        }
        // Gil-Werman: o[i] = min(w[i..i+19]), i = 0..15
        float suf[20];
        suf[19] = w[19];
        #pragma unroll
        for (int k = 18; k >= 0; --k) suf[k] = fminf(w[k], suf[k + 1]);
        float pre[15];
        pre[0] = w[20];
        #pragma unroll
        for (int k = 1; k < 15; ++k) pre[k] = fminf(pre[k - 1], w[20 + k]);
        float o[16];
        o[0] = suf[0];
        #pragma unroll
        for (int i = 1; i < 16; ++i) o[i] = fminf(suf[i], pre[i - 1]);

        float* dst = &hm[r * LSTR + (q << 4)];
        #pragma unroll
        for (int k = 0; k < 8; ++k)
            *(float2*)(dst + 2 * k) = make_float2(o[2 * k], o[2 * k + 1]);
    }
    __syncthreads();

    // ---- Phase 2: vertical min(20), run of 16 rows per thread ----
    float sum = 0.f;
    {
        int j  = t & 63;
        int i0 = (t >> 6) << 4;
        float w[35];
        #pragma unroll
        for (int d = 0; d < 35; ++d) w[d] = hm[(i0 + d) * LSTR + j];
        float suf[20];
        suf[19] = w[19];
        #pragma unroll
        for (int k = 18; k >= 0; --k) suf[k] = fminf(w[k], suf[k + 1]);
        float pre[15];
        pre[0] = w[20];
        #pragma unroll
        for (int k = 1; k < 15; ++k) pre[k] = fminf(pre[k - 1], w[20 + k]);
        sum = suf[0];
        #pragma unroll
        for (int i = 1; i < 16; ++i) sum += fminf(suf[i], pre[i - 1]);
    }

    // ---- Block partial (deterministic) ----
    #pragma unroll
    for (int off = 32; off; off >>= 1) sum += __shfl_down(sum, off);
    if ((t & 63) == 0) red[t >> 6] = sum;
    __syncthreads();
    if (t == 0) {
        float ps = red[0] + red[1] + red[2] + red[3];
        int bid = (blockIdx.z * NBY + blockIdx.y) * NBX + blockIdx.x;
        partials[bid] = ps;
        __threadfence();                       // release partials
        unsigned old = atomicAdd(counter, 1u); // device-scope
        lastflag = (old == NBLK - 1);
    }
    __syncthreads();

    // ---- Last block: final reduce (fixed order -> deterministic) ----
    if (lastflag) {
        __threadfence();                       // acquire partials
        float s = 0.f;
        for (int i = t; i < NBLK; i += 256) s += partials[i];
        #pragma unroll
        for (int off = 32; off; off >>= 1) s += __shfl_down(s, off);
        if ((t & 63) == 0) red[t >> 6] = s;
        __syncthreads();
        if (t == 0) {
            float total = red[0] + red[1] + red[2] + red[3];
            float mean = total / (float)((long long)BATCH * CH);
            out[0] = fabsf(1.0f - mean);
        }
    }
}

extern "C" void kernel_launch(void* const* d_in, const int* in_sizes, int n_in,
                              void* d_out, int out_size, void* d_ws, size_t ws_size,
                              hipStream_t stream) {
    const float* x = (const float*)d_in[0];
    float* out = (float*)d_out;
    float* partials = (float*)d_ws;                          // 2048 f32
    unsigned* counter = (unsigned*)((char*)d_ws + NBLK * 4); // 1 u32

    hipMemsetAsync(counter, 0, 4, stream);   // replay-safe ticket reset
    dim3 grid(NBX, NBY, BATCH);              // 8 x 8 x 32 = 2048 blocks
    dark_fused_kernel<<<grid, 256, 0, stream>>>(x, partials, counter, out);
}

// Round 6
// 124.882 us; speedup vs baseline: 1.0406x; 1.0406x over previous
//
#include <hip/hip_runtime.h>
#include <math.h>

// x[32,3,512,512] f32 -> |1 - mean over (b,h,w) of min over (c, 20x20 window,
// replicate pad pl=9 pr=10)|.
//
// Single fused kernel, 384 threads/block, 64x64 outputs/block (2048 blocks).
// R5 lesson: the horizontal-pass body (e[40]/suf/pre arrays) MUST be
// straight-line code executed once per thread -- wrapping it in a strided
// task loop made the compiler demote arrays to scratch (VGPR=44, 128 MB
// spill traffic, 3.6x regression). 384 threads >= 332 tasks -> no loop.
//
//   phase 1 (t<332): channel-min + horizontal sliding-min(20) straight from
//            global (coalesced float4, clamped aligned base), Gil-Werman
//            run of 16 -> LDS hm[83][66] (stride 66: column reads 2-way=free).
//            Replicate-pad rows baked in via row clamp.
//   phase 2 (t<256): vertical sliding-min(20), Gil-Werman run of 16, f32 sum.
//   finish:  block partial -> d_ws; last block (atomic ticket, fenced)
//            reduces 2048 partials in fixed order -> |1 - mean|.

#define BATCH 32
#define HH 512
#define WW 512
#define CH (HH * WW)
#define NBX 8
#define NBY 8
#define NBLK (NBX * NBY * BATCH)   // 2048
#define NTHR 384
#define LSTR 66                    // LDS row stride in floats

__device__ __forceinline__ float fmin3(float a, float b, float c) {
    return fminf(fminf(a, b), c);
}

__launch_bounds__(NTHR)
__global__ void dark_fused_kernel(const float* __restrict__ x,
                                  float* __restrict__ partials,
                                  unsigned* __restrict__ counter,
                                  float* __restrict__ out)
{
    __shared__ float hm[83 * LSTR];   // 21912 B
    __shared__ float red[6];
    __shared__ int lastflag;

    const int b  = blockIdx.z;
    const int h0 = blockIdx.y * 64;
    const int w0 = blockIdx.x * 64;
    const int t  = threadIdx.x;
    const float* xb = x + (size_t)b * 3 * CH;

    // ---- Phase 1: channel-min + horizontal min(20) -> LDS (one task/thread)
    if (t < 83 * 4) {
        int r = t >> 2;                  // LDS row 0..82
        int q = t & 3;                   // 16-col quad 0..3
        int gr = h0 - 9 + r; gr = gr < 0 ? 0 : (gr > HH - 1 ? HH - 1 : gr);
        int jg0 = w0 + (q << 4);         // global col of first output
        int grun = jg0 >> 4;             // global run index 0..31
        const float* row = xb + gr * WW;
        int cb  = jg0 - 12;
        int cbc = cb < 0 ? 0 : (cb > WW - 40 ? WW - 40 : cb);  // 0 or 472
        const float4* p0 = (const float4*)(row + cbc);
        const float4* p1 = (const float4*)(row + cbc + CH);
        const float4* p2 = (const float4*)(row + cbc + 2 * CH);
        float e[40];
        #pragma unroll
        for (int k = 0; k < 10; ++k) {
            float4 a = p0[k], bb = p1[k], c = p2[k];
            e[4 * k + 0] = fmin3(a.x, bb.x, c.x);
            e[4 * k + 1] = fmin3(a.y, bb.y, c.y);
            e[4 * k + 2] = fmin3(a.z, bb.z, c.z);
            e[4 * k + 3] = fmin3(a.w, bb.w, c.w);
        }
        // w[d] = channel-min at clamped global col (jg0 + d - 9), d=0..34
        float w[35];
        if (grun == 0) {
            #pragma unroll
            for (int d = 0; d < 35; ++d) w[d] = e[d < 9 ? 0 : d - 9];
        } else if (grun == 31) {
            #pragma unroll
            for (int d = 0; d < 35; ++d) w[d] = e[d + 15 > 39 ? 39 : d + 15];
        } else {
            #pragma unroll
            for (int d = 0; d < 35; ++d) w[d] = e[d + 3];
        }
        // Gil-Werman: o[i] = min(w[i..i+19]), i = 0..15
        float suf[20];
        suf[19] = w[19];
        #pragma unroll
        for (int k = 18; k >= 0; --k) suf[k] = fminf(w[k], suf[k + 1]);
        float pre[15];
        pre[0] = w[20];
        #pragma unroll
        for (int k = 1; k < 15; ++k) pre[k] = fminf(pre[k - 1], w[20 + k]);
        float o[16];
        o[0] = suf[0];
        #pragma unroll
        for (int i = 1; i < 16; ++i) o[i] = fminf(suf[i], pre[i - 1]);

        float* dst = &hm[r * LSTR + (q << 4)];
        #pragma unroll
        for (int k = 0; k < 8; ++k)
            *(float2*)(dst + 2 * k) = make_float2(o[2 * k], o[2 * k + 1]);
    }
    __syncthreads();

    // ---- Phase 2: vertical min(20), run of 16 rows (one task/thread) ----
    float sum = 0.f;
    if (t < 256) {
        int j  = t & 63;
        int i0 = (t >> 6) << 4;
        float w[35];
        #pragma unroll
        for (int d = 0; d < 35; ++d) w[d] = hm[(i0 + d) * LSTR + j];
        float suf[20];
        suf[19] = w[19];
        #pragma unroll
        for (int k = 18; k >= 0; --k) suf[k] = fminf(w[k], suf[k + 1]);
        float pre[15];
        pre[0] = w[20];
        #pragma unroll
        for (int k = 1; k < 15; ++k) pre[k] = fminf(pre[k - 1], w[20 + k]);
        sum = suf[0];
        #pragma unroll
        for (int i = 1; i < 16; ++i) sum += fminf(suf[i], pre[i - 1]);
    }

    // ---- Block partial (deterministic) ----
    #pragma unroll
    for (int off = 32; off; off >>= 1) sum += __shfl_down(sum, off);
    if ((t & 63) == 0) red[t >> 6] = sum;
    __syncthreads();
    if (t == 0) {
        float ps = ((red[0] + red[1]) + (red[2] + red[3])) + (red[4] + red[5]);
        int bid = (blockIdx.z * NBY + blockIdx.y) * NBX + blockIdx.x;
        partials[bid] = ps;
        __threadfence();                       // release partials
        unsigned old = atomicAdd(counter, 1u); // device-scope
        lastflag = (old == NBLK - 1);
    }
    __syncthreads();

    // ---- Last block: final reduce (fixed order -> deterministic) ----
    if (lastflag) {
        __threadfence();                       // acquire partials
        float s = 0.f;
        for (int i = t; i < NBLK; i += NTHR) s += partials[i];
        #pragma unroll
        for (int off = 32; off; off >>= 1) s += __shfl_down(s, off);
        if ((t & 63) == 0) red[t >> 6] = s;
        __syncthreads();
        if (t == 0) {
            float total = ((red[0] + red[1]) + (red[2] + red[3])) + (red[4] + red[5]);
            float mean = total / (float)((long long)BATCH * CH);
            out[0] = fabsf(1.0f - mean);
        }
    }
}

extern "C" void kernel_launch(void* const* d_in, const int* in_sizes, int n_in,
                              void* d_out, int out_size, void* d_ws, size_t ws_size,
                              hipStream_t stream) {
    const float* x = (const float*)d_in[0];
    float* out = (float*)d_out;
    float* partials = (float*)d_ws;                          // 2048 f32
    unsigned* counter = (unsigned*)((char*)d_ws + NBLK * 4); // 1 u32

    hipMemsetAsync(counter, 0, 4, stream);   // replay-safe ticket reset
    dim3 grid(NBX, NBY, BATCH);              // 8 x 8 x 32 = 2048 blocks
    dark_fused_kernel<<<grid, NTHR, 0, stream>>>(x, partials, counter, out);
}

// Round 7
// 66.362 us; speedup vs baseline: 1.9582x; 1.8818x over previous
//
#include <hip/hip_runtime.h>
#include <hip/hip_fp16.h>
#include <math.h>

// x[32,3,512,512] f32 -> |1 - mean over (b,h,w) of min over (c, 20x20 window,
// replicate pad pl=9 pr=10)|.
//
// Two-kernel split (R4 structure, measured 36 us) + ticket-merged final
// reduce. R5/R6 lesson: the fully-fused LDS variant gets its e[40]/w[35]
// arrays demoted to scratch (VGPR=36..44 observed) and runs latency-bound
// at ~125 us -- do NOT refuse without shrinking per-thread arrays to run-of-8.
//
//   K1: channel-min + horizontal sliding-min(20), run of 16 cols/thread,
//       coalesced float4 global reads (clamped aligned base), Gil-Werman;
//       writes hm[32,512,512] f16 into d_ws.  (identical to R4 K1)
//   K2: vertical sliding-min(20) on hm as packed f16x2 (v_pk_min_f16),
//       f32 accumulate -> block partials; last block (atomic ticket, fenced)
//       reduces the 1024 partials in fixed order -> |1 - mean|.

#define BATCH 32
#define HH 512
#define WW 512
#define CH (HH * WW)
#define K2BLK 1024

__device__ __forceinline__ float fmin3(float a, float b, float c) {
    return fminf(fminf(a, b), c);
}

__device__ __forceinline__ unsigned pkmin(unsigned a, unsigned b) {
    unsigned r;
    asm volatile("v_pk_min_f16 %0, %1, %2" : "=v"(r) : "v"(a), "v"(b));
    return r;
}

__device__ __forceinline__ float2 unpack_h2(unsigned u) {
    __half2 h;
    *(unsigned*)&h = u;
    return __half22float2(h);
}

// ---------------- K1: horizontal pass ----------------
// thread -> (b, h, run): run = gid&31 (16 cols), h = (gid>>5)&511, b = gid>>14
__launch_bounds__(256)
__global__ void hmin_kernel(const float* __restrict__ x, __half* __restrict__ hm)
{
    int gid = blockIdx.x * 256 + threadIdx.x;
    int r = gid & 31;
    int h = (gid >> 5) & (HH - 1);
    int b = gid >> 14;
    int j0 = r << 4;

    const float* row = x + (size_t)b * 3 * CH + (size_t)h * WW;

    // Load 40 floats per channel from clamped aligned base, channel-min into e.
    int cb  = j0 - 12;
    int cbc = cb < 0 ? 0 : (cb > WW - 40 ? WW - 40 : cb);   // 0 or 472 at edges
    const float4* p0 = (const float4*)(row + cbc);
    const float4* p1 = (const float4*)(row + cbc + CH);
    const float4* p2 = (const float4*)(row + cbc + 2 * CH);
    float e[40];
    #pragma unroll
    for (int k = 0; k < 10; ++k) {
        float4 a = p0[k], bb = p1[k], c = p2[k];
        e[4 * k + 0] = fmin3(a.x, bb.x, c.x);
        e[4 * k + 1] = fmin3(a.y, bb.y, c.y);
        e[4 * k + 2] = fmin3(a.z, bb.z, c.z);
        e[4 * k + 3] = fmin3(a.w, bb.w, c.w);
    }

    // w[d] = channel-min at clamped col (j0 + d - 9), d = 0..34
    float w[35];
    if (r == 0) {
        #pragma unroll
        for (int d = 0; d < 35; ++d) w[d] = e[d < 9 ? 0 : d - 9];
    } else if (r == 31) {
        #pragma unroll
        for (int d = 0; d < 35; ++d) w[d] = e[d + 15 > 39 ? 39 : d + 15];
    } else {
        #pragma unroll
        for (int d = 0; d < 35; ++d) w[d] = e[d + 3];
    }

    // Gil-Werman: o[i] = min(w[i..i+19]), i = 0..15
    float suf[20];
    suf[19] = w[19];
    #pragma unroll
    for (int k = 18; k >= 0; --k) suf[k] = fminf(w[k], suf[k + 1]);
    float pre[15];
    pre[0] = w[20];
    #pragma unroll
    for (int k = 1; k < 15; ++k) pre[k] = fminf(pre[k - 1], w[20 + k]);
    float o[16];
    o[0] = suf[0];
    #pragma unroll
    for (int i = 1; i < 16; ++i) o[i] = fminf(suf[i], pre[i - 1]);

    // Pack to f16 and store 32 contiguous bytes.
    __half2 hp[8];
    #pragma unroll
    for (int k = 0; k < 8; ++k)
        hp[k] = __halves2half2(__float2half_rn(o[2 * k]), __float2half_rn(o[2 * k + 1]));
    float4* dst = (float4*)(hm + ((size_t)b * HH + h) * WW + j0);
    dst[0] = *(float4*)&hp[0];
    dst[1] = *(float4*)&hp[4];
}

// ---------------- K2: vertical pass + partials + ticket final reduce ----
// thread -> (b, rrun, jj): jj = gid&255 (half2 col pair), rrun = (gid>>8)&31
__launch_bounds__(256)
__global__ void vmin_kernel(const unsigned* __restrict__ hm2,
                            float* __restrict__ partials,
                            unsigned* __restrict__ counter,
                            float* __restrict__ out)
{
    int gid = blockIdx.x * 256 + threadIdx.x;
    int jj = gid & 255;
    int rr = (gid >> 8) & 31;
    int b  = gid >> 13;
    int i0 = rr << 4;

    const unsigned* col = hm2 + (size_t)b * (CH / 2) + jj;

    int rb  = i0 - 9;
    int rbc = rb < 0 ? 0 : (rb > HH - 35 ? HH - 35 : rb);   // 0 or 477 at edges
    unsigned ld[35];
    #pragma unroll
    for (int d = 0; d < 35; ++d) ld[d] = col[(rbc + d) * (WW / 2)];

    unsigned w[35];
    if (rr == 0) {
        #pragma unroll
        for (int d = 0; d < 35; ++d) w[d] = ld[d < 9 ? 0 : d - 9];
    } else if (rr == 31) {
        #pragma unroll
        for (int d = 0; d < 35; ++d) w[d] = ld[d + 10 > 34 ? 34 : d + 10];
    } else {
        #pragma unroll
        for (int d = 0; d < 35; ++d) w[d] = ld[d];
    }

    unsigned suf[20];
    suf[19] = w[19];
    #pragma unroll
    for (int k = 18; k >= 0; --k) suf[k] = pkmin(w[k], suf[k + 1]);
    unsigned pre[15];
    pre[0] = w[20];
    #pragma unroll
    for (int k = 1; k < 15; ++k) pre[k] = pkmin(pre[k - 1], w[20 + k]);

    float sum;
    {
        float2 f = unpack_h2(suf[0]);
        sum = f.x + f.y;
    }
    #pragma unroll
    for (int i = 1; i < 16; ++i) {
        float2 f = unpack_h2(pkmin(suf[i], pre[i - 1]));
        sum += f.x + f.y;
    }

    // deterministic block reduction
    __shared__ float red[4];
    __shared__ int lastflag;
    #pragma unroll
    for (int off = 32; off; off >>= 1) sum += __shfl_down(sum, off);
    if ((threadIdx.x & 63) == 0) red[threadIdx.x >> 6] = sum;
    __syncthreads();
    if (threadIdx.x == 0) {
        partials[blockIdx.x] = (red[0] + red[1]) + (red[2] + red[3]);
        __threadfence();                        // release partials
        unsigned old = atomicAdd(counter, 1u);  // device-scope
        lastflag = (old == K2BLK - 1);
    }
    __syncthreads();

    // last block: fixed-order reduce of 1024 partials -> deterministic
    if (lastflag) {
        __threadfence();                        // acquire partials
        float s = 0.f;
        for (int i = threadIdx.x; i < K2BLK; i += 256) s += partials[i];
        #pragma unroll
        for (int off = 32; off; off >>= 1) s += __shfl_down(s, off);
        if ((threadIdx.x & 63) == 0) red[threadIdx.x >> 6] = s;
        __syncthreads();
        if (threadIdx.x == 0) {
            float total = (red[0] + red[1]) + (red[2] + red[3]);
            float mean = total / (float)((long long)BATCH * CH);
            out[0] = fabsf(1.0f - mean);
        }
    }
}

extern "C" void kernel_launch(void* const* d_in, const int* in_sizes, int n_in,
                              void* d_out, int out_size, void* d_ws, size_t ws_size,
                              hipStream_t stream) {
    const float* x = (const float*)d_in[0];
    float* out = (float*)d_out;

    __half* hm = (__half*)d_ws;                                        // 16.78 MB
    float* partials = (float*)((char*)d_ws + (size_t)BATCH * CH * 2);  // 1024 f32
    unsigned* counter = (unsigned*)(partials + K2BLK);                 // 1 u32

    hipMemsetAsync(counter, 0, 4, stream);   // replay-safe ticket reset

    // K1: 32*512*32 threads = 2048 blocks
    hmin_kernel<<<2048, 256, 0, stream>>>(x, hm);
    // K2: 32*32*256 threads = 1024 blocks (+ fused final reduce)
    vmin_kernel<<<K2BLK, 256, 0, stream>>>((const unsigned*)hm, partials, counter, out);
}

// Round 8
// 61.061 us; speedup vs baseline: 2.1282x; 1.0868x over previous
//
#include <hip/hip_runtime.h>
#include <hip/hip_fp16.h>
#include <math.h>

// x[32,3,512,512] f32 -> |1 - mean over (b,h,w) of min over (c, 20x20 window,
// replicate pad pl=9 pr=10)|.
//
// Two-kernel split (R4 structure) + ticket-merged final reduce.
// R7 lesson: a graph-captured 4-byte hipMemsetAsync costs ~58 us/replay
// (fillBufferAligned dispatch with barrier semantics) -- NEVER memset for a
// ticket counter. K1 resets the counter instead (dispatch boundary = release,
// so K2 always starts with counter==0).
// R5/R6 lesson: fully-fused LDS variant demotes e[40]/w[35] to scratch
// (VGPR=36..44) and runs latency-bound at ~125 us -- keep the split.
//
//   K1: channel-min + horizontal sliding-min(20), run of 16 cols/thread,
//       coalesced float4 global reads (clamped aligned base), Gil-Werman;
//       writes hm[32,512,512] f16 into d_ws. gid==0 resets ticket counter.
//   K2: vertical sliding-min(20) on hm as packed f16x2 (v_pk_min_f16),
//       f32 accumulate -> block partials; last block (atomic ticket, fenced)
//       reduces the 1024 partials in fixed order -> |1 - mean|.

#define BATCH 32
#define HH 512
#define WW 512
#define CH (HH * WW)
#define K2BLK 1024

__device__ __forceinline__ float fmin3(float a, float b, float c) {
    return fminf(fminf(a, b), c);
}

__device__ __forceinline__ unsigned pkmin(unsigned a, unsigned b) {
    unsigned r;
    asm volatile("v_pk_min_f16 %0, %1, %2" : "=v"(r) : "v"(a), "v"(b));
    return r;
}

__device__ __forceinline__ float2 unpack_h2(unsigned u) {
    __half2 h;
    *(unsigned*)&h = u;
    return __half22float2(h);
}

// ---------------- K1: horizontal pass ----------------
// thread -> (b, h, run): run = gid&31 (16 cols), h = (gid>>5)&511, b = gid>>14
__launch_bounds__(256)
__global__ void hmin_kernel(const float* __restrict__ x, __half* __restrict__ hm,
                            unsigned* __restrict__ counter)
{
    int gid = blockIdx.x * 256 + threadIdx.x;
    if (gid == 0) atomicExch(counter, 0u);   // ticket reset for K2 (replay-safe)
    int r = gid & 31;
    int h = (gid >> 5) & (HH - 1);
    int b = gid >> 14;
    int j0 = r << 4;

    const float* row = x + (size_t)b * 3 * CH + (size_t)h * WW;

    // Load 40 floats per channel from clamped aligned base, channel-min into e.
    int cb  = j0 - 12;
    int cbc = cb < 0 ? 0 : (cb > WW - 40 ? WW - 40 : cb);   // 0 or 472 at edges
    const float4* p0 = (const float4*)(row + cbc);
    const float4* p1 = (const float4*)(row + cbc + CH);
    const float4* p2 = (const float4*)(row + cbc + 2 * CH);
    float e[40];
    #pragma unroll
    for (int k = 0; k < 10; ++k) {
        float4 a = p0[k], bb = p1[k], c = p2[k];
        e[4 * k + 0] = fmin3(a.x, bb.x, c.x);
        e[4 * k + 1] = fmin3(a.y, bb.y, c.y);
        e[4 * k + 2] = fmin3(a.z, bb.z, c.z);
        e[4 * k + 3] = fmin3(a.w, bb.w, c.w);
    }

    // w[d] = channel-min at clamped col (j0 + d - 9), d = 0..34
    float w[35];
    if (r == 0) {
        #pragma unroll
        for (int d = 0; d < 35; ++d) w[d] = e[d < 9 ? 0 : d - 9];
    } else if (r == 31) {
        #pragma unroll
        for (int d = 0; d < 35; ++d) w[d] = e[d + 15 > 39 ? 39 : d + 15];
    } else {
        #pragma unroll
        for (int d = 0; d < 35; ++d) w[d] = e[d + 3];
    }

    // Gil-Werman: o[i] = min(w[i..i+19]), i = 0..15
    float suf[20];
    suf[19] = w[19];
    #pragma unroll
    for (int k = 18; k >= 0; --k) suf[k] = fminf(w[k], suf[k + 1]);
    float pre[15];
    pre[0] = w[20];
    #pragma unroll
    for (int k = 1; k < 15; ++k) pre[k] = fminf(pre[k - 1], w[20 + k]);
    float o[16];
    o[0] = suf[0];
    #pragma unroll
    for (int i = 1; i < 16; ++i) o[i] = fminf(suf[i], pre[i - 1]);

    // Pack to f16 and store 32 contiguous bytes.
    __half2 hp[8];
    #pragma unroll
    for (int k = 0; k < 8; ++k)
        hp[k] = __halves2half2(__float2half_rn(o[2 * k]), __float2half_rn(o[2 * k + 1]));
    float4* dst = (float4*)(hm + ((size_t)b * HH + h) * WW + j0);
    dst[0] = *(float4*)&hp[0];
    dst[1] = *(float4*)&hp[4];
}

// ---------------- K2: vertical pass + partials + ticket final reduce ----
// thread -> (b, rrun, jj): jj = gid&255 (half2 col pair), rrun = (gid>>8)&31
__launch_bounds__(256)
__global__ void vmin_kernel(const unsigned* __restrict__ hm2,
                            float* __restrict__ partials,
                            unsigned* __restrict__ counter,
                            float* __restrict__ out)
{
    int gid = blockIdx.x * 256 + threadIdx.x;
    int jj = gid & 255;
    int rr = (gid >> 8) & 31;
    int b  = gid >> 13;
    int i0 = rr << 4;

    const unsigned* col = hm2 + (size_t)b * (CH / 2) + jj;

    int rb  = i0 - 9;
    int rbc = rb < 0 ? 0 : (rb > HH - 35 ? HH - 35 : rb);   // 0 or 477 at edges
    unsigned ld[35];
    #pragma unroll
    for (int d = 0; d < 35; ++d) ld[d] = col[(rbc + d) * (WW / 2)];

    unsigned w[35];
    if (rr == 0) {
        #pragma unroll
        for (int d = 0; d < 35; ++d) w[d] = ld[d < 9 ? 0 : d - 9];
    } else if (rr == 31) {
        #pragma unroll
        for (int d = 0; d < 35; ++d) w[d] = ld[d + 10 > 34 ? 34 : d + 10];
    } else {
        #pragma unroll
        for (int d = 0; d < 35; ++d) w[d] = ld[d];
    }

    unsigned suf[20];
    suf[19] = w[19];
    #pragma unroll
    for (int k = 18; k >= 0; --k) suf[k] = pkmin(w[k], suf[k + 1]);
    unsigned pre[15];
    pre[0] = w[20];
    #pragma unroll
    for (int k = 1; k < 15; ++k) pre[k] = pkmin(pre[k - 1], w[20 + k]);

    float sum;
    {
        float2 f = unpack_h2(suf[0]);
        sum = f.x + f.y;
    }
    #pragma unroll
    for (int i = 1; i < 16; ++i) {
        float2 f = unpack_h2(pkmin(suf[i], pre[i - 1]));
        sum += f.x + f.y;
    }

    // deterministic block reduction
    __shared__ float red[4];
    __shared__ int lastflag;
    #pragma unroll
    for (int off = 32; off; off >>= 1) sum += __shfl_down(sum, off);
    if ((threadIdx.x & 63) == 0) red[threadIdx.x >> 6] = sum;
    __syncthreads();
    if (threadIdx.x == 0) {
        partials[blockIdx.x] = (red[0] + red[1]) + (red[2] + red[3]);
        __threadfence();                        // release partials
        unsigned old = atomicAdd(counter, 1u);  // device-scope
        lastflag = (old == K2BLK - 1);
    }
    __syncthreads();

    // last block: fixed-order reduce of 1024 partials -> deterministic
    if (lastflag) {
        __threadfence();                        // acquire partials
        float s = 0.f;
        for (int i = threadIdx.x; i < K2BLK; i += 256) s += partials[i];
        #pragma unroll
        for (int off = 32; off; off >>= 1) s += __shfl_down(s, off);
        if ((threadIdx.x & 63) == 0) red[threadIdx.x >> 6] = s;
        __syncthreads();
        if (threadIdx.x == 0) {
            float total = (red[0] + red[1]) + (red[2] + red[3]);
            float mean = total / (float)((long long)BATCH * CH);
            out[0] = fabsf(1.0f - mean);
        }
    }
}

extern "C" void kernel_launch(void* const* d_in, const int* in_sizes, int n_in,
                              void* d_out, int out_size, void* d_ws, size_t ws_size,
                              hipStream_t stream) {
    const float* x = (const float*)d_in[0];
    float* out = (float*)d_out;

    __half* hm = (__half*)d_ws;                                        // 16.78 MB
    float* partials = (float*)((char*)d_ws + (size_t)BATCH * CH * 2);  // 1024 f32
    unsigned* counter = (unsigned*)(partials + K2BLK);                 // 1 u32

    // K1: 32*512*32 threads = 2048 blocks (also resets ticket counter)
    hmin_kernel<<<2048, 256, 0, stream>>>(x, hm, counter);
    // K2: 32*32*256 threads = 1024 blocks (+ fused final reduce)
    vmin_kernel<<<K2BLK, 256, 0, stream>>>((const unsigned*)hm, partials, counter, out);
}

// Round 9
// 36.475 us; speedup vs baseline: 3.5627x; 1.6740x over previous
//
#include <hip/hip_runtime.h>
#include <hip/hip_fp16.h>
#include <math.h>

// x[32,3,512,512] f32 -> |1 - mean over (b,h,w) of min over (c, 20x20 window,
// replicate pad pl=9 pr=10)|.
//
// Separable, barrier-free, LDS-free 3-kernel split (R4 structure, measured
// 36.3 us -- best known).
// Journal of failed "improvements" (do not repeat):
//   R5/R6: fully-fused LDS variant -> compiler demoted e[40]/w[35] to
//          scratch (VGPR 36..44), latency-bound, ~125 us. A re-try needs an
//          explicit VGPR budget (__launch_bounds__(N, <=2)) verified via
//          -Rpass-analysis before benching.
//   R7: in-graph 4-byte hipMemsetAsync for a ticket counter -> ~58 us
//          fillBufferAligned dispatch per replay.
//   R8: ticket/last-block reduce (atomicAdd + __threadfence per block) ->
//          +25 us (device-scope fence across non-coherent XCD L2s x1024
//          blocks) vs the ~5 us saved by dropping K3.
//
//   K1: channel-min + horizontal sliding-min(20), run of 16 cols/thread,
//       coalesced float4 global reads (clamped aligned base), Gil-Werman;
//       writes hm[32,512,512] f16 into d_ws.
//   K2: vertical sliding-min(20) on hm as packed f16x2 (v_pk_min_f16),
//       f32 accumulate -> 1024 block partials.
//   K3: single-block deterministic reduce -> |1 - mean|.

#define BATCH 32
#define HH 512
#define WW 512
#define CH (HH * WW)

__device__ __forceinline__ float fmin3(float a, float b, float c) {
    return fminf(fminf(a, b), c);
}

__device__ __forceinline__ unsigned pkmin(unsigned a, unsigned b) {
    unsigned r;
    asm volatile("v_pk_min_f16 %0, %1, %2" : "=v"(r) : "v"(a), "v"(b));
    return r;
}

__device__ __forceinline__ float2 unpack_h2(unsigned u) {
    __half2 h;
    *(unsigned*)&h = u;
    return __half22float2(h);
}

// ---------------- K1: horizontal pass ----------------
// thread -> (b, h, run): run = gid&31 (16 cols), h = (gid>>5)&511, b = gid>>14
__launch_bounds__(256)
__global__ void hmin_kernel(const float* __restrict__ x, __half* __restrict__ hm)
{
    int gid = blockIdx.x * 256 + threadIdx.x;
    int r = gid & 31;
    int h = (gid >> 5) & (HH - 1);
    int b = gid >> 14;
    int j0 = r << 4;

    const float* row = x + (size_t)b * 3 * CH + (size_t)h * WW;

    // Load 40 floats per channel from clamped aligned base, channel-min into e.
    int cb  = j0 - 12;
    int cbc = cb < 0 ? 0 : (cb > WW - 40 ? WW - 40 : cb);   // 0 or 472 at edges
    const float4* p0 = (const float4*)(row + cbc);
    const float4* p1 = (const float4*)(row + cbc + CH);
    const float4* p2 = (const float4*)(row + cbc + 2 * CH);
    float e[40];
    #pragma unroll
    for (int k = 0; k < 10; ++k) {
        float4 a = p0[k], bb = p1[k], c = p2[k];
        e[4 * k + 0] = fmin3(a.x, bb.x, c.x);
        e[4 * k + 1] = fmin3(a.y, bb.y, c.y);
        e[4 * k + 2] = fmin3(a.z, bb.z, c.z);
        e[4 * k + 3] = fmin3(a.w, bb.w, c.w);
    }

    // w[d] = channel-min at clamped col (j0 + d - 9), d = 0..34
    float w[35];
    if (r == 0) {
        #pragma unroll
        for (int d = 0; d < 35; ++d) w[d] = e[d < 9 ? 0 : d - 9];
    } else if (r == 31) {
        #pragma unroll
        for (int d = 0; d < 35; ++d) w[d] = e[d + 15 > 39 ? 39 : d + 15];
    } else {
        #pragma unroll
        for (int d = 0; d < 35; ++d) w[d] = e[d + 3];
    }

    // Gil-Werman: o[i] = min(w[i..i+19]), i = 0..15
    float suf[20];
    suf[19] = w[19];
    #pragma unroll
    for (int k = 18; k >= 0; --k) suf[k] = fminf(w[k], suf[k + 1]);
    float pre[15];
    pre[0] = w[20];
    #pragma unroll
    for (int k = 1; k < 15; ++k) pre[k] = fminf(pre[k - 1], w[20 + k]);
    float o[16];
    o[0] = suf[0];
    #pragma unroll
    for (int i = 1; i < 16; ++i) o[i] = fminf(suf[i], pre[i - 1]);

    // Pack to f16 and store 32 contiguous bytes.
    __half2 hp[8];
    #pragma unroll
    for (int k = 0; k < 8; ++k)
        hp[k] = __halves2half2(__float2half_rn(o[2 * k]), __float2half_rn(o[2 * k + 1]));
    float4* dst = (float4*)(hm + ((size_t)b * HH + h) * WW + j0);
    dst[0] = *(float4*)&hp[0];
    dst[1] = *(float4*)&hp[4];
}

// ---------------- K2: vertical pass + partial sums ----------------
// thread -> (b, rrun, jj): jj = gid&255 (half2 col pair), rrun = (gid>>8)&31
__launch_bounds__(256)
__global__ void vmin_kernel(const unsigned* __restrict__ hm2,
                            float* __restrict__ partials)
{
    int gid = blockIdx.x * 256 + threadIdx.x;
    int jj = gid & 255;
    int rr = (gid >> 8) & 31;
    int b  = gid >> 13;
    int i0 = rr << 4;

    const unsigned* col = hm2 + (size_t)b * (CH / 2) + jj;

    int rb  = i0 - 9;
    int rbc = rb < 0 ? 0 : (rb > HH - 35 ? HH - 35 : rb);   // 0 or 477 at edges
    unsigned ld[35];
    #pragma unroll
    for (int d = 0; d < 35; ++d) ld[d] = col[(rbc + d) * (WW / 2)];

    unsigned w[35];
    if (rr == 0) {
        #pragma unroll
        for (int d = 0; d < 35; ++d) w[d] = ld[d < 9 ? 0 : d - 9];
    } else if (rr == 31) {
        #pragma unroll
        for (int d = 0; d < 35; ++d) w[d] = ld[d + 10 > 34 ? 34 : d + 10];
    } else {
        #pragma unroll
        for (int d = 0; d < 35; ++d) w[d] = ld[d];
    }

    unsigned suf[20];
    suf[19] = w[19];
    #pragma unroll
    for (int k = 18; k >= 0; --k) suf[k] = pkmin(w[k], suf[k + 1]);
    unsigned pre[15];
    pre[0] = w[20];
    #pragma unroll
    for (int k = 1; k < 15; ++k) pre[k] = pkmin(pre[k - 1], w[20 + k]);

    float sum;
    {
        float2 f = unpack_h2(suf[0]);
        sum = f.x + f.y;
    }
    #pragma unroll
    for (int i = 1; i < 16; ++i) {
        float2 f = unpack_h2(pkmin(suf[i], pre[i - 1]));
        sum += f.x + f.y;
    }

    // deterministic block reduction
    #pragma unroll
    for (int off = 32; off; off >>= 1) sum += __shfl_down(sum, off);
    __shared__ float red[4];
    if ((threadIdx.x & 63) == 0) red[threadIdx.x >> 6] = sum;
    __syncthreads();
    if (threadIdx.x == 0)
        partials[blockIdx.x] = (red[0] + red[1]) + (red[2] + red[3]);
}

// ---------------- K3: final reduce ----------------
__launch_bounds__(256)
__global__ void dark_reduce_kernel(const float* __restrict__ partials, int n,
                                   float* __restrict__ out)
{
    __shared__ float red[4];
    int t = threadIdx.x;
    float s = 0.f;
    for (int i = t; i < n; i += 256) s += partials[i];
    #pragma unroll
    for (int off = 32; off; off >>= 1) s += __shfl_down(s, off);
    if ((t & 63) == 0) red[t >> 6] = s;
    __syncthreads();
    if (t == 0) {
        float total = (red[0] + red[1]) + (red[2] + red[3]);
        float mean = total / (float)((long long)BATCH * CH);
        out[0] = fabsf(1.0f - mean);
    }
}

extern "C" void kernel_launch(void* const* d_in, const int* in_sizes, int n_in,
                              void* d_out, int out_size, void* d_ws, size_t ws_size,
                              hipStream_t stream) {
    const float* x = (const float*)d_in[0];
    float* out = (float*)d_out;

    __half* hm = (__half*)d_ws;                                        // 16.78 MB
    float* partials = (float*)((char*)d_ws + (size_t)BATCH * CH * 2);  // 1024 f32

    // K1: 32*512*32 threads = 2048 blocks
    hmin_kernel<<<2048, 256, 0, stream>>>(x, hm);
    // K2: 32*32*256 threads = 1024 blocks
    vmin_kernel<<<1024, 256, 0, stream>>>((const unsigned*)hm, partials);
    dark_reduce_kernel<<<1, 256, 0, stream>>>(partials, 1024, out);
}